// Round 4
// baseline (1246.144 us; speedup 1.0000x reference)
//
#include <hip/hip_runtime.h>
#include <cfloat>

// Problem: B=16,N=2048,D=512 tokens vs K=8192 codebook; out = codebook[argmin dist]
#define TOKENS 32768
#define DDIM   512
#define KCODES 8192

#define CAP    160        // candidate list capacity per token
#define MARGIN 2.0f       // >> 2*max bf16 score error (~0.6 max, 0.072 std)

// ---- workspace layout (bytes) ----
#define ZEBF_OFF   0                                   // bf16 ze  [32768][512]
#define CBBF_OFF   (TOKENS * DDIM * 2)                 // bf16 cb  [8192][512]
#define CNORM_OFF  (CBBF_OFF + KCODES * DDIM * 2)      // fp32 ||c||^2 [8192]
#define CNT_OFF    (CNORM_OFF + KCODES * 4)            // int   cnt [32768]
#define CANDI_OFF  (CNT_OFF + TOKENS * 4)              // int   cand idx [32768][CAP]
#define CANDS_OFF  (CANDI_OFF + TOKENS * CAP * 4)      // float cand s~  [32768][CAP]
#define WS_REQ     ((size_t)(CANDS_OFF + TOKENS * CAP * 4))   // 84,049,920 B

typedef short bf16x8 __attribute__((ext_vector_type(8)));   // 8 bf16 (4 VGPRs)
typedef float f32x4  __attribute__((ext_vector_type(4)));

__device__ __forceinline__ unsigned short f2bf(float f) {
    union { float f; unsigned int u; } v; v.f = f;
    unsigned int u = v.u;
    return (unsigned short)((u + 0x7fffu + ((u >> 16) & 1u)) >> 16);  // RNE
}

// ---- fp32 -> bf16 conversion (8 elems/thread) -------------------------------
__global__ __launch_bounds__(256) void convert_kernel(const float* __restrict__ src,
                                                      unsigned short* __restrict__ dst,
                                                      int n8) {
    int i = blockIdx.x * 256 + threadIdx.x;
    if (i >= n8) return;
    float4 a = ((const float4*)src)[i * 2];
    float4 b = ((const float4*)src)[i * 2 + 1];
    bf16x8 o;
    o[0] = (short)f2bf(a.x); o[1] = (short)f2bf(a.y);
    o[2] = (short)f2bf(a.z); o[3] = (short)f2bf(a.w);
    o[4] = (short)f2bf(b.x); o[5] = (short)f2bf(b.y);
    o[6] = (short)f2bf(b.z); o[7] = (short)f2bf(b.w);
    *(bf16x8*)&dst[(size_t)i * 8] = o;
}

// ---- codebook row squared norms (fp32, exact) -------------------------------
__global__ __launch_bounds__(256) void cnorm_kernel(const float* __restrict__ cb,
                                                    float* __restrict__ cnorm) {
    int row  = blockIdx.x * 4 + (threadIdx.x >> 6);
    int lane = threadIdx.x & 63;
    const float* r = cb + (size_t)row * DDIM;
    float s = 0.f;
    #pragma unroll
    for (int d = lane; d < DDIM; d += 64) { float v = r[d]; s += v * v; }
    #pragma unroll
    for (int off = 32; off > 0; off >>= 1) s += __shfl_down(s, off, 64);
    if (lane == 0) cnorm[row] = s;
}

// ---- fragment load: A/B layout row=lane&15, k=(lane>>4)*8+j  ----------------
// One global_load_dwordx4 per fragment; wave reads 16 rows x 64 B (dense).
__device__ __forceinline__ void load_frags(const unsigned short* __restrict__ aB,
                                           const unsigned short* __restrict__ bB,
                                           int ko, bf16x8* af, bf16x8* bfr) {
    #pragma unroll
    for (int rt = 0; rt < 4; ++rt)
        af[rt] = *(const bf16x8*)(aB + (size_t)rt * 16 * DDIM + ko);
    #pragma unroll
    for (int ct = 0; ct < 8; ++ct)
        bfr[ct] = *(const bf16x8*)(bB + (size_t)ct * 16 * DDIM + ko);
}

__device__ __forceinline__ void mfma_step(const bf16x8* af, const bf16x8* bfr,
                                          f32x4 acc[4][8]) {
    #pragma unroll
    for (int rt = 0; rt < 4; ++rt)
        #pragma unroll
        for (int ct = 0; ct < 8; ++ct)
            acc[rt][ct] = __builtin_amdgcn_mfma_f32_16x16x32_bf16(
                af[rt], bfr[ct], acc[rt][ct], 0, 0, 0);
}

// ---- main: barrier-free streaming MFMA + margin candidate collection --------
// Block = 256 tokens x 128 codes, 4 waves; wave w owns tokens [blk*256+w*64, +64)
// and ALL 128 codes (4x8 grid of 16x16x32 tiles, acc[4][8]). No LDS: fragments
// stream global->VGPR double-buffered; intra-block B reuse is served by L1.
__global__ __launch_bounds__(256, 2) void vq_mfma_kernel(
        const unsigned short* __restrict__ zebf,
        const unsigned short* __restrict__ cbbf,
        const float* __restrict__ cnorm,
        int* __restrict__ cnt,
        int* __restrict__ candI,
        float* __restrict__ candS) {
    const int tid  = threadIdx.x;
    const int w    = tid >> 6;
    const int lane = tid & 63;
    const int tok0  = blockIdx.y * 256 + w * 64;   // this wave's 64 tokens
    const int code0 = blockIdx.x * 128;

    const unsigned short* aB = zebf + (size_t)(tok0  + (lane & 15)) * DDIM + (lane >> 4) * 8;
    const unsigned short* bB = cbbf + (size_t)(code0 + (lane & 15)) * DDIM + (lane >> 4) * 8;

    f32x4 acc[4][8];
    const f32x4 zero = {0.f, 0.f, 0.f, 0.f};
    #pragma unroll
    for (int i = 0; i < 4; ++i)
        #pragma unroll
        for (int j = 0; j < 8; ++j) acc[i][j] = zero;

    bf16x8 afA[4], bfA[8], afB[4], bfB[8];
    load_frags(aB, bB, 0, afA, bfA);

    #pragma unroll
    for (int dk = 0; dk < DDIM; dk += 64) {
        load_frags(aB, bB, dk + 32, afB, bfB);   // in flight while afA/bfA compute
        mfma_step(afA, bfA, acc);
        if (dk + 64 < DDIM)
            load_frags(aB, bB, dk + 64, afA, bfA);
        mfma_step(afB, bfB, acc);
    }

    // ---- epilogue: C/D layout col=lane&15, row=(lane>>4)*4+reg ----
    float cn[8];
    #pragma unroll
    for (int ct = 0; ct < 8; ++ct)
        cn[ct] = cnorm[code0 + ct * 16 + (lane & 15)];

    #pragma unroll
    for (int rt = 0; rt < 4; ++rt)
        #pragma unroll
        for (int r = 0; r < 4; ++r) {
            // wave-local rowmin over all 128 codes of this block
            float m = cn[0] - 2.f * acc[rt][0][r];
            #pragma unroll
            for (int ct = 1; ct < 8; ++ct)
                m = fminf(m, cn[ct] - 2.f * acc[rt][ct][r]);
            #pragma unroll
            for (int off = 1; off < 16; off <<= 1)
                m = fminf(m, __shfl_xor(m, off, 64));
            float thr = m + MARGIN;   // conservative superset; wave min always collected

            int token = tok0 + rt * 16 + (lane >> 4) * 4 + r;
            #pragma unroll
            for (int ct = 0; ct < 8; ++ct) {
                float s = cn[ct] - 2.f * acc[rt][ct][r];
                if (s <= thr) {
                    int pos = atomicAdd(&cnt[token], 1);
                    if (pos < CAP) {
                        candI[(size_t)token * CAP + pos] = code0 + ct * 16 + (lane & 15);
                        candS[(size_t)token * CAP + pos] = s;
                    }
                }
            }
        }
}

// ---- exact fp32 rescore of survivors + gather (one wave per token) ----------
__global__ __launch_bounds__(64) void rescore_kernel(
        const float* __restrict__ ze, const float* __restrict__ cb,
        const float* __restrict__ cnorm, const int* __restrict__ cnt,
        const int* __restrict__ candI, const float* __restrict__ candS,
        float* __restrict__ out) {
    const int t    = blockIdx.x;
    const int lane = threadIdx.x;

    float4 za = *(const float4*)&ze[(size_t)t * DDIM + lane * 8];
    float4 zb = *(const float4*)&ze[(size_t)t * DDIM + lane * 8 + 4];

    int n = cnt[t];
    bool ovf = (n > CAP) || (n <= 0);

    float best = FLT_MAX;
    int   bidx = 0x7fffffff;

    if (!ovf) {
        // m~ = global min of s~ (every wave's rowmin is in the list)
        float m = FLT_MAX;
        for (int e = lane; e < n; e += 64)
            m = fminf(m, candS[(size_t)t * CAP + e]);
        #pragma unroll
        for (int off = 32; off > 0; off >>= 1)
            m = fminf(m, __shfl_xor(m, off, 64));
        float thr = m + MARGIN;

        for (int base = 0; base < n; base += 64) {
            int e = base + lane;
            int myI = 0; float sv = FLT_MAX;
            if (e < n) { myI = candI[(size_t)t * CAP + e]; sv = candS[(size_t)t * CAP + e]; }
            unsigned long long mask = __ballot(e < n && sv <= thr);
            while (mask) {
                int b = __ffsll((long long)mask) - 1;
                mask &= mask - 1;
                int code = __shfl(myI, b, 64);
                const float* row = cb + (size_t)code * DDIM + lane * 8;
                float4 ca = *(const float4*)row;
                float4 cc = *(const float4*)(row + 4);
                float d = za.x*ca.x + za.y*ca.y + za.z*ca.z + za.w*ca.w
                        + zb.x*cc.x + zb.y*cc.y + zb.z*cc.z + zb.w*cc.w;
                #pragma unroll
                for (int off = 32; off > 0; off >>= 1) d += __shfl_xor(d, off, 64);
                float s = cnorm[code] - 2.f * d;
                if (s < best || (s == best && code < bidx)) { best = s; bidx = code; }
            }
        }
    } else {
        for (int code = 0; code < KCODES; ++code) {
            const float* row = cb + (size_t)code * DDIM + lane * 8;
            float4 ca = *(const float4*)row;
            float4 cc = *(const float4*)(row + 4);
            float d = za.x*ca.x + za.y*ca.y + za.z*ca.z + za.w*ca.w
                    + zb.x*cc.x + zb.y*cc.y + zb.z*cc.z + zb.w*cc.w;
            #pragma unroll
            for (int off = 32; off > 0; off >>= 1) d += __shfl_xor(d, off, 64);
            float s = cnorm[code] - 2.f * d;
            if (s < best || (s == best && code < bidx)) { best = s; bidx = code; }
        }
    }

    // gather winner row
    const float* src = cb + (size_t)bidx * DDIM + lane * 8;
    float4 o0 = *(const float4*)src;
    float4 o1 = *(const float4*)(src + 4);
    *(float4*)&out[(size_t)t * DDIM + lane * 8]     = o0;
    *(float4*)&out[(size_t)t * DDIM + lane * 8 + 4] = o1;
}

// ============================ R1 fallback path ===============================
#define TM 64
#define TN 64
#define BK 32
#define LDS_STRIDE (TM + 4)

__global__ __launch_bounds__(256) void vq_fallback_kernel(const float* __restrict__ ze,
                                                          const float* __restrict__ cb,
                                                          const float* __restrict__ cnorm,
                                                          float* __restrict__ out) {
    __shared__ float At[BK][LDS_STRIDE];
    __shared__ float Bt[BK][LDS_STRIDE];
    __shared__ float rv[TM][16];
    __shared__ int   ri[TM][16];
    __shared__ int   best_s[TM];

    const int tid = threadIdx.x;
    const int tx  = tid & 15;
    const int ty  = tid >> 4;
    const int token_base = blockIdx.x * TM;
    const int sc = tid & 31;
    const int sr = tid >> 5;

    float bestv[4] = {FLT_MAX, FLT_MAX, FLT_MAX, FLT_MAX};
    int   besti[4] = {0, 0, 0, 0};

    for (int ctile = 0; ctile < KCODES; ctile += TN) {
        float acc[4][4] = {{0.f}};
        for (int dk = 0; dk < DDIM; dk += BK) {
            __syncthreads();
            #pragma unroll
            for (int p = 0; p < 8; ++p) {
                int r = p * 8 + sr;
                At[sc][r] = ze[(size_t)(token_base + r) * DDIM + dk + sc];
                Bt[sc][r] = cb[(size_t)(ctile + r) * DDIM + dk + sc];
            }
            __syncthreads();
            #pragma unroll
            for (int d = 0; d < BK; ++d) {
                float a[4], b[4];
                *(float4*)a = *(const float4*)&At[d][ty * 4];
                *(float4*)b = *(const float4*)&Bt[d][tx * 4];
                #pragma unroll
                for (int i = 0; i < 4; ++i)
                    #pragma unroll
                    for (int j = 0; j < 4; ++j)
                        acc[i][j] += a[i] * b[j];
            }
        }
        #pragma unroll
        for (int j = 0; j < 4; ++j) {
            int code = ctile + tx * 4 + j;
            float cnv = cnorm[code];
            #pragma unroll
            for (int i = 0; i < 4; ++i) {
                float s = cnv - 2.f * acc[i][j];
                if (s < bestv[i]) { bestv[i] = s; besti[i] = code; }
            }
        }
    }
    #pragma unroll
    for (int i = 0; i < 4; ++i) {
        rv[ty * 4 + i][tx] = bestv[i];
        ri[ty * 4 + i][tx] = besti[i];
    }
    __syncthreads();
    if (tid < TM) {
        float bv = rv[tid][0]; int bi = ri[tid][0];
        #pragma unroll
        for (int x = 1; x < 16; ++x) {
            float v = rv[tid][x]; int ix = ri[tid][x];
            if (v < bv || (v == bv && ix < bi)) { bv = v; bi = ix; }
        }
        best_s[tid] = bi;
    }
    __syncthreads();
    const int gr   = tid >> 7;
    const int gcol = (tid & 127) * 4;
    for (int rr = 0; rr < TM; rr += 2) {
        int tk  = rr + gr;
        int src = best_s[tk];
        float4 v = *(const float4*)&cb[(size_t)src * DDIM + gcol];
        *(float4*)&out[(size_t)(token_base + tk) * DDIM + gcol] = v;
    }
}

extern "C" void kernel_launch(void* const* d_in, const int* in_sizes, int n_in,
                              void* d_out, int out_size, void* d_ws, size_t ws_size,
                              hipStream_t stream) {
    const float* ze = (const float*)d_in[0];   // [32768][512]
    const float* cb = (const float*)d_in[1];   // [8192][512]
    float* out      = (float*)d_out;

    if (ws_size < WS_REQ) {
        // not enough scratch for the MFMA pipeline: R1 exact-fp32 path
        float* cnorm = (float*)d_ws;
        cnorm_kernel<<<KCODES / 4, 256, 0, stream>>>(cb, cnorm);
        vq_fallback_kernel<<<TOKENS / TM, 256, 0, stream>>>(ze, cb, cnorm, out);
        return;
    }

    char* ws = (char*)d_ws;
    unsigned short* zebf = (unsigned short*)(ws + ZEBF_OFF);
    unsigned short* cbbf = (unsigned short*)(ws + CBBF_OFF);
    float* cnorm = (float*)(ws + CNORM_OFF);
    int*   cnt   = (int*)(ws + CNT_OFF);
    int*   candI = (int*)(ws + CANDI_OFF);
    float* candS = (float*)(ws + CANDS_OFF);

    convert_kernel<<<(TOKENS * DDIM / 8) / 256, 256, 0, stream>>>(ze, zebf, TOKENS * DDIM / 8);
    convert_kernel<<<(KCODES * DDIM / 8) / 256, 256, 0, stream>>>(cb, cbbf, KCODES * DDIM / 8);
    cnorm_kernel<<<KCODES / 4, 256, 0, stream>>>(cb, cnorm);
    hipMemsetAsync(cnt, 0, TOKENS * sizeof(int), stream);

    dim3 grid(KCODES / 128, TOKENS / 256);
    vq_mfma_kernel<<<grid, 256, 0, stream>>>(zebf, cbbf, cnorm, cnt, candI, candS);

    rescore_kernel<<<TOKENS, 64, 0, stream>>>(ze, cb, cnorm, cnt, candI, candS, out);
}

// Round 5
// 797.870 us; speedup vs baseline: 1.5618x; 1.5618x over previous
//
#include <hip/hip_runtime.h>
#include <cfloat>

// Problem: B=16,N=2048,D=512 tokens vs K=8192 codebook; out = codebook[argmin dist]
#define TOKENS 32768
#define DDIM   512
#define KCODES 8192

#define CAP    160        // candidate list capacity per token
#define MARGIN 2.0f       // >> 2*max bf16 score error (~0.6 max, 0.072 std)

// ---- workspace layout (bytes) ----
#define ZEBF_OFF   0                                   // bf16 ze  [32768][512]
#define CBBF_OFF   (TOKENS * DDIM * 2)                 // bf16 cb  [8192][512]
#define CNORM_OFF  (CBBF_OFF + KCODES * DDIM * 2)      // fp32 ||c||^2 [8192]
#define CNT_OFF    (CNORM_OFF + KCODES * 4)            // int   cnt [32768]
#define CANDI_OFF  (CNT_OFF + TOKENS * 4)              // int   cand idx [32768][CAP]
#define CANDS_OFF  (CANDI_OFF + TOKENS * CAP * 4)      // float cand s~  [32768][CAP]
#define WS_REQ     ((size_t)(CANDS_OFF + TOKENS * CAP * 4))   // 84,049,920 B

typedef short bf16x8 __attribute__((ext_vector_type(8)));   // 8 bf16 (4 VGPRs)
typedef float f32x4  __attribute__((ext_vector_type(4)));

// async global->LDS, 16B per lane; LDS dest must be wave-uniform base + lane*16
__device__ __forceinline__ void gld16(const void* g, void* l) {
    __builtin_amdgcn_global_load_lds(
        (const __attribute__((address_space(1))) void*)g,
        (__attribute__((address_space(3))) void*)l,
        16, 0, 0);
}

__device__ __forceinline__ unsigned short f2bf(float f) {
    union { float f; unsigned int u; } v; v.f = f;
    unsigned int u = v.u;
    return (unsigned short)((u + 0x7fffu + ((u >> 16) & 1u)) >> 16);  // RNE
}

// ---- fp32 -> bf16 conversion (8 elems/thread) -------------------------------
__global__ __launch_bounds__(256) void convert_kernel(const float* __restrict__ src,
                                                      unsigned short* __restrict__ dst,
                                                      int n8) {
    int i = blockIdx.x * 256 + threadIdx.x;
    if (i >= n8) return;
    float4 a = ((const float4*)src)[i * 2];
    float4 b = ((const float4*)src)[i * 2 + 1];
    bf16x8 o;
    o[0] = (short)f2bf(a.x); o[1] = (short)f2bf(a.y);
    o[2] = (short)f2bf(a.z); o[3] = (short)f2bf(a.w);
    o[4] = (short)f2bf(b.x); o[5] = (short)f2bf(b.y);
    o[6] = (short)f2bf(b.z); o[7] = (short)f2bf(b.w);
    *(bf16x8*)&dst[(size_t)i * 8] = o;
}

// ---- codebook row squared norms (fp32, exact) -------------------------------
__global__ __launch_bounds__(256) void cnorm_kernel(const float* __restrict__ cb,
                                                    float* __restrict__ cnorm) {
    int row  = blockIdx.x * 4 + (threadIdx.x >> 6);
    int lane = threadIdx.x & 63;
    const float* r = cb + (size_t)row * DDIM;
    float s = 0.f;
    #pragma unroll
    for (int d = lane; d < DDIM; d += 64) { float v = r[d]; s += v * v; }
    #pragma unroll
    for (int off = 32; off > 0; off >>= 1) s += __shfl_down(s, off, 64);
    if (lane == 0) cnorm[row] = s;
}

// ---- main: bf16 MFMA scores + margin candidate collection -------------------
// Block = 256 tokens x 128 codes, 4 waves. Wave w: tokens [tok0+w*64, +64),
// ALL 128 codes -> wave tile 64x128 via 4x8 mfma_f32_16x16x32_bf16, acc[4][8].
// Rowmin is wave-local (no cross-wave combine, no epilogue barrier).
//
// Block scheduling (L2 locality): 1-D grid of 8192 blocks, decomposed as
//   xcd      = bid & 7          (round-robin XCD heuristic)
//   panel    = (bid>>3) >> 7    cb panel of 1024 codes (1 MB bf16, L2-resident)
//   tb_local = ((bid>>3)&127)>>3, cb_local = (bid>>3)&7  (codes iterate fastest)
// Concurrent blocks share ~1.25 MB (cb panel + ze chunk) per L2 -> global
// staging traffic drops ~10x vs x-major order.
__global__ __launch_bounds__(256, 2) void vq_mfma_kernel(
        const unsigned short* __restrict__ zebf,
        const unsigned short* __restrict__ cbbf,
        const float* __restrict__ cnorm,
        int* __restrict__ cnt,
        int* __restrict__ candI,
        float* __restrict__ candS) {
    // LDS rows of 64 bf16 (128 B = 8 slots of 16 B), XOR-swizzled:
    // phys_slot = logical_slot ^ (row & 7)  (swizzle applied on global ptr side)
    __shared__ unsigned short Ab[256 * 64];   // 32 KB
    __shared__ unsigned short Bb[128 * 64];   // 16 KB

    const int tid  = threadIdx.x;
    const int w    = tid >> 6;
    const int lane = tid & 63;

    const int bid      = blockIdx.x;
    const int xcd      = bid & 7;
    const int loc      = bid >> 3;        // 0..1023
    const int panel    = loc >> 7;        // 0..7
    const int l2i      = loc & 127;
    const int tb_local = l2i >> 3;        // 0..15
    const int cb_local = l2i & 7;         // 0..7
    const int token_blk = tb_local * 8 + xcd;     // 0..127
    const int code_blk  = panel * 8 + cb_local;   // 0..63

    const int tok0  = token_blk * 256;
    const int code0 = code_blk * 128;

    f32x4 acc[4][8];
    const f32x4 zero = {0.f, 0.f, 0.f, 0.f};
    #pragma unroll
    for (int i = 0; i < 4; ++i)
        #pragma unroll
        for (int j = 0; j < 8; ++j) acc[i][j] = zero;

    for (int dk = 0; dk < DDIM; dk += 64) {
        __syncthreads();   // previous chunk's reads done before overwrite
        #pragma unroll
        for (int i = 0; i < 8; ++i) {
            int L    = ((i * 4 + w) * 1024) + lane * 16;  // byte offset, wave-contig
            int row  = L >> 7;                            // 128 B per LDS row
            int phys = (L >> 4) & 7;
            int slog = phys ^ (row & 7);
            gld16(zebf + (size_t)(tok0 + row) * DDIM + dk + slog * 8, (char*)Ab + L);
            if (i < 4)
                gld16(cbbf + (size_t)(code0 + row) * DDIM + dk + slog * 8, (char*)Bb + L);
        }
        __syncthreads();   // vmcnt(0) drain before barrier (compiler-emitted)

        #pragma unroll
        for (int kk = 0; kk < 2; ++kk) {
            bf16x8 af[4], bfr[8];
            int slog = kk * 4 + (lane >> 4);
            #pragma unroll
            for (int rt = 0; rt < 4; ++rt) {
                int row  = w * 64 + rt * 16 + (lane & 15);
                int phys = slog ^ (row & 7);
                af[rt] = *(const bf16x8*)(Ab + row * 64 + phys * 8);
            }
            #pragma unroll
            for (int ct = 0; ct < 8; ++ct) {
                int row  = ct * 16 + (lane & 15);
                int phys = slog ^ (row & 7);
                bfr[ct] = *(const bf16x8*)(Bb + row * 64 + phys * 8);
            }
            #pragma unroll
            for (int rt = 0; rt < 4; ++rt)
                #pragma unroll
                for (int ct = 0; ct < 8; ++ct)
                    acc[rt][ct] = __builtin_amdgcn_mfma_f32_16x16x32_bf16(
                        af[rt], bfr[ct], acc[rt][ct], 0, 0, 0);
        }
    }

    // ---- epilogue: C/D layout col=lane&15, row=(lane>>4)*4+reg ----
    float cn[8];
    #pragma unroll
    for (int ct = 0; ct < 8; ++ct)
        cn[ct] = cnorm[code0 + ct * 16 + (lane & 15)];

    #pragma unroll
    for (int rt = 0; rt < 4; ++rt)
        #pragma unroll
        for (int r = 0; r < 4; ++r) {
            // wave-local rowmin over all 128 codes of this block
            float m = cn[0] - 2.f * acc[rt][0][r];
            #pragma unroll
            for (int ct = 1; ct < 8; ++ct)
                m = fminf(m, cn[ct] - 2.f * acc[rt][ct][r]);
            #pragma unroll
            for (int off = 1; off < 16; off <<= 1)
                m = fminf(m, __shfl_xor(m, off, 64));
            float thr = m + MARGIN;   // conservative superset; wave min always collected

            int token = tok0 + w * 64 + rt * 16 + (lane >> 4) * 4 + r;
            #pragma unroll
            for (int ct = 0; ct < 8; ++ct) {
                float s = cn[ct] - 2.f * acc[rt][ct][r];
                if (s <= thr) {
                    int pos = atomicAdd(&cnt[token], 1);
                    if (pos < CAP) {
                        candI[(size_t)token * CAP + pos] = code0 + ct * 16 + (lane & 15);
                        candS[(size_t)token * CAP + pos] = s;
                    }
                }
            }
        }
}

// ---- exact fp32 rescore of survivors + gather (one wave per token) ----------
__global__ __launch_bounds__(64) void rescore_kernel(
        const float* __restrict__ ze, const float* __restrict__ cb,
        const float* __restrict__ cnorm, const int* __restrict__ cnt,
        const int* __restrict__ candI, const float* __restrict__ candS,
        float* __restrict__ out) {
    const int t    = blockIdx.x;
    const int lane = threadIdx.x;

    float4 za = *(const float4*)&ze[(size_t)t * DDIM + lane * 8];
    float4 zb = *(const float4*)&ze[(size_t)t * DDIM + lane * 8 + 4];

    int n = cnt[t];
    bool ovf = (n > CAP) || (n <= 0);

    float best = FLT_MAX;
    int   bidx = 0x7fffffff;

    if (!ovf) {
        // m~ = global min of s~ (every wave's rowmin is in the list)
        float m = FLT_MAX;
        for (int e = lane; e < n; e += 64)
            m = fminf(m, candS[(size_t)t * CAP + e]);
        #pragma unroll
        for (int off = 32; off > 0; off >>= 1)
            m = fminf(m, __shfl_xor(m, off, 64));
        float thr = m + MARGIN;

        for (int base = 0; base < n; base += 64) {
            int e = base + lane;
            int myI = 0; float sv = FLT_MAX;
            if (e < n) { myI = candI[(size_t)t * CAP + e]; sv = candS[(size_t)t * CAP + e]; }
            unsigned long long mask = __ballot(e < n && sv <= thr);
            while (mask) {
                int b = __ffsll((long long)mask) - 1;
                mask &= mask - 1;
                int code = __shfl(myI, b, 64);
                const float* row = cb + (size_t)code * DDIM + lane * 8;
                float4 ca = *(const float4*)row;
                float4 cc = *(const float4*)(row + 4);
                float d = za.x*ca.x + za.y*ca.y + za.z*ca.z + za.w*ca.w
                        + zb.x*cc.x + zb.y*cc.y + zb.z*cc.z + zb.w*cc.w;
                #pragma unroll
                for (int off = 32; off > 0; off >>= 1) d += __shfl_xor(d, off, 64);
                float s = cnorm[code] - 2.f * d;
                if (s < best || (s == best && code < bidx)) { best = s; bidx = code; }
            }
        }
    } else {
        for (int code = 0; code < KCODES; ++code) {
            const float* row = cb + (size_t)code * DDIM + lane * 8;
            float4 ca = *(const float4*)row;
            float4 cc = *(const float4*)(row + 4);
            float d = za.x*ca.x + za.y*ca.y + za.z*ca.z + za.w*ca.w
                    + zb.x*cc.x + zb.y*cc.y + zb.z*cc.z + zb.w*cc.w;
            #pragma unroll
            for (int off = 32; off > 0; off >>= 1) d += __shfl_xor(d, off, 64);
            float s = cnorm[code] - 2.f * d;
            if (s < best || (s == best && code < bidx)) { best = s; bidx = code; }
        }
    }

    // gather winner row
    const float* src = cb + (size_t)bidx * DDIM + lane * 8;
    float4 o0 = *(const float4*)src;
    float4 o1 = *(const float4*)(src + 4);
    *(float4*)&out[(size_t)t * DDIM + lane * 8]     = o0;
    *(float4*)&out[(size_t)t * DDIM + lane * 8 + 4] = o1;
}

// ============================ R1 fallback path ===============================
#define TM 64
#define TN 64
#define BK 32
#define LDS_STRIDE (TM + 4)

__global__ __launch_bounds__(256) void vq_fallback_kernel(const float* __restrict__ ze,
                                                          const float* __restrict__ cb,
                                                          const float* __restrict__ cnorm,
                                                          float* __restrict__ out) {
    __shared__ float At[BK][LDS_STRIDE];
    __shared__ float Bt[BK][LDS_STRIDE];
    __shared__ float rv[TM][16];
    __shared__ int   ri[TM][16];
    __shared__ int   best_s[TM];

    const int tid = threadIdx.x;
    const int tx  = tid & 15;
    const int ty  = tid >> 4;
    const int token_base = blockIdx.x * TM;
    const int sc = tid & 31;
    const int sr = tid >> 5;

    float bestv[4] = {FLT_MAX, FLT_MAX, FLT_MAX, FLT_MAX};
    int   besti[4] = {0, 0, 0, 0};

    for (int ctile = 0; ctile < KCODES; ctile += TN) {
        float acc[4][4] = {{0.f}};
        for (int dk = 0; dk < DDIM; dk += BK) {
            __syncthreads();
            #pragma unroll
            for (int p = 0; p < 8; ++p) {
                int r = p * 8 + sr;
                At[sc][r] = ze[(size_t)(token_base + r) * DDIM + dk + sc];
                Bt[sc][r] = cb[(size_t)(ctile + r) * DDIM + dk + sc];
            }
            __syncthreads();
            #pragma unroll
            for (int d = 0; d < BK; ++d) {
                float a[4], b[4];
                *(float4*)a = *(const float4*)&At[d][ty * 4];
                *(float4*)b = *(const float4*)&Bt[d][tx * 4];
                #pragma unroll
                for (int i = 0; i < 4; ++i)
                    #pragma unroll
                    for (int j = 0; j < 4; ++j)
                        acc[i][j] += a[i] * b[j];
            }
        }
        #pragma unroll
        for (int j = 0; j < 4; ++j) {
            int code = ctile + tx * 4 + j;
            float cnv = cnorm[code];
            #pragma unroll
            for (int i = 0; i < 4; ++i) {
                float s = cnv - 2.f * acc[i][j];
                if (s < bestv[i]) { bestv[i] = s; besti[i] = code; }
            }
        }
    }
    #pragma unroll
    for (int i = 0; i < 4; ++i) {
        rv[ty * 4 + i][tx] = bestv[i];
        ri[ty * 4 + i][tx] = besti[i];
    }
    __syncthreads();
    if (tid < TM) {
        float bv = rv[tid][0]; int bi = ri[tid][0];
        #pragma unroll
        for (int x = 1; x < 16; ++x) {
            float v = rv[tid][x]; int ix = ri[tid][x];
            if (v < bv || (v == bv && ix < bi)) { bv = v; bi = ix; }
        }
        best_s[tid] = bi;
    }
    __syncthreads();
    const int gr   = tid >> 7;
    const int gcol = (tid & 127) * 4;
    for (int rr = 0; rr < TM; rr += 2) {
        int tk  = rr + gr;
        int src = best_s[tk];
        float4 v = *(const float4*)&cb[(size_t)src * DDIM + gcol];
        *(float4*)&out[(size_t)(token_base + tk) * DDIM + gcol] = v;
    }
}

extern "C" void kernel_launch(void* const* d_in, const int* in_sizes, int n_in,
                              void* d_out, int out_size, void* d_ws, size_t ws_size,
                              hipStream_t stream) {
    const float* ze = (const float*)d_in[0];   // [32768][512]
    const float* cb = (const float*)d_in[1];   // [8192][512]
    float* out      = (float*)d_out;

    if (ws_size < WS_REQ) {
        // not enough scratch for the MFMA pipeline: R1 exact-fp32 path
        float* cnorm = (float*)d_ws;
        cnorm_kernel<<<KCODES / 4, 256, 0, stream>>>(cb, cnorm);
        vq_fallback_kernel<<<TOKENS / TM, 256, 0, stream>>>(ze, cb, cnorm, out);
        return;
    }

    char* ws = (char*)d_ws;
    unsigned short* zebf = (unsigned short*)(ws + ZEBF_OFF);
    unsigned short* cbbf = (unsigned short*)(ws + CBBF_OFF);
    float* cnorm = (float*)(ws + CNORM_OFF);
    int*   cnt   = (int*)(ws + CNT_OFF);
    int*   candI = (int*)(ws + CANDI_OFF);
    float* candS = (float*)(ws + CANDS_OFF);

    convert_kernel<<<(TOKENS * DDIM / 8) / 256, 256, 0, stream>>>(ze, zebf, TOKENS * DDIM / 8);
    convert_kernel<<<(KCODES * DDIM / 8) / 256, 256, 0, stream>>>(cb, cbbf, KCODES * DDIM / 8);
    cnorm_kernel<<<KCODES / 4, 256, 0, stream>>>(cb, cnorm);
    hipMemsetAsync(cnt, 0, TOKENS * sizeof(int), stream);

    // 1-D grid; block->tile mapping (panel/XCD swizzle) computed in-kernel
    vq_mfma_kernel<<<(TOKENS / 256) * (KCODES / 128), 256, 0, stream>>>(
        zebf, cbbf, cnorm, cnt, candI, candS);

    rescore_kernel<<<TOKENS, 64, 0, stream>>>(ze, cb, cnorm, cnt, candI, candS, out);
}